// Round 1
// baseline (1507.655 us; speedup 1.0000x reference)
//
#include <hip/hip_runtime.h>
#include <math.h>

#define N_   2
#define M_   65536
#define P_   3
#define L_   6
#define CPL_ 32
#define C_   192
#define HID_ 64
#define HW_  256   // H = W = 256

// ---------------------------------------------------------------------------
// Transpose planes (N,P,C,H,W) -> (N,P,H*W,C)  (channel-last for coalesced
// per-pixel channel reads in the point kernel).
// ---------------------------------------------------------------------------
__global__ __launch_bounds__(256) void transpose_kernel(
    const float* __restrict__ in, float* __restrict__ out)
{
    __shared__ float tile[32][193];   // [pix][chan], pad 193 -> conflict-free
    const int np   = blockIdx.x >> 11;          // 2048 pixel-tiles per slice
    const int pix0 = (blockIdx.x & 2047) << 5;  // tile*32 (32 | 256, same row)
    const float* src = in  + (size_t)np * C_ * 65536;
    float*       dst = out + (size_t)np * 65536 * C_;
    const int t = threadIdx.x;

    #pragma unroll
    for (int it = 0; it < 24; ++it) {           // 192*32 / 256 = 24
        int idx = it * 256 + t;
        int Cc  = idx >> 5;
        int px  = idx & 31;
        tile[px][Cc] = src[(size_t)Cc * 65536 + pix0 + px];  // coalesced read
    }
    __syncthreads();
    #pragma unroll
    for (int it = 0; it < 24; ++it) {
        int idx = it * 256 + t;
        int Cc  = idx % 192;
        int px  = idx / 192;
        dst[(size_t)(pix0 + px) * C_ + Cc] = tile[px][Cc];   // coalesced write
    }
}

// ---------------------------------------------------------------------------
// One wave (64 lanes) per point. Lane ell owns channels {ell, ell+64, ell+128}.
// ---------------------------------------------------------------------------
template <bool TR>
__global__ __launch_bounds__(256) void point_kernel(
    const float* __restrict__ planes,   // TR: (NP, HW2, C)  else (NP, C, HW2)
    const float* __restrict__ coords,
    const float* __restrict__ w1,       // (L, CPL, HID)
    const float* __restrict__ b1,       // (L, HID)
    const float* __restrict__ w2,       // (L, HID, 5)
    const float* __restrict__ b2,       // (L, 5)
    const float* __restrict__ betap,    // (1,)
    float* __restrict__ out)            // (N, M, 17)
{
    __shared__ float feat_s[4][C_];
    __shared__ __align__(16) float dz_s[4][L_ * HID_];

    const int wave  = threadIdx.x >> 6;
    const int lane  = threadIdx.x & 63;
    const int point = (blockIdx.x << 2) + wave;
    const int n     = point >> 16;      // M = 65536

    const float cx = coords[point * 3 + 0];
    const float cy = coords[point * 3 + 1];
    const float cz = coords[point * 3 + 2];

    // scale = 2/BOX_WARP = 1.0; plane projections (permutation inverses):
    // p0:(x,y)  p1:(x,z)  p2:(z,y)
    const float pjx[3] = {cx, cx, cz};
    const float pjy[3] = {cy, cz, cy};

    float wx0[3], wx1[3], wy0[3], wy1[3];
    int   pixi[3][4];
    float vmk[3][4];
    #pragma unroll
    for (int p = 0; p < 3; ++p) {
        float px = (pjx[p] + 1.0f) * 128.0f - 0.5f;
        float py = (pjy[p] + 1.0f) * 128.0f - 0.5f;
        float x0f = floorf(px), y0f = floorf(py);
        wx1[p] = px - x0f; wx0[p] = 1.0f - wx1[p];
        wy1[p] = py - y0f; wy0[p] = 1.0f - wy1[p];
        int x0 = (int)x0f, y0 = (int)y0f;
        int x1 = x0 + 1,  y1 = y0 + 1;
        int xc0 = min(max(x0, 0), 255), xc1 = min(max(x1, 0), 255);
        int yc0 = min(max(y0, 0), 255), yc1 = min(max(y1, 0), 255);
        float vx0 = (x0 >= 0 && x0 < 256) ? 1.f : 0.f;
        float vx1 = (x1 >= 0 && x1 < 256) ? 1.f : 0.f;
        float vy0 = (y0 >= 0 && y0 < 256) ? 1.f : 0.f;
        float vy1 = (y1 >= 0 && y1 < 256) ? 1.f : 0.f;
        pixi[p][0] = yc0 * 256 + xc0; vmk[p][0] = vx0 * vy0;  // (x0,y0)
        pixi[p][1] = yc0 * 256 + xc1; vmk[p][1] = vx1 * vy0;  // (x1,y0)
        pixi[p][2] = yc1 * 256 + xc0; vmk[p][2] = vx0 * vy1;  // (x0,y1)
        pixi[p][3] = yc1 * 256 + xc1; vmk[p][3] = vx1 * vy1;  // (x1,y1)
    }

    // ---- gather: 3 planes x 4 corners x 3 channels/lane ----
    float g[3][4][3];
    #pragma unroll
    for (int p = 0; p < 3; ++p) {
        #pragma unroll
        for (int ij = 0; ij < 4; ++ij) {
            #pragma unroll
            for (int k = 0; k < 3; ++k) {
                int Cc = lane + 64 * k;
                int addr;
                if (TR) addr = ((n * 3 + p) * 65536 + pixi[p][ij]) * C_ + Cc;
                else    addr = ((n * 3 + p) * C_ + Cc) * 65536 + pixi[p][ij];
                g[p][ij][k] = planes[addr] * vmk[p][ij];
            }
        }
    }

    // ---- feat = mean over planes of bilinear combos ----
    #pragma unroll
    for (int k = 0; k < 3; ++k) {
        float f = 0.f;
        #pragma unroll
        for (int p = 0; p < 3; ++p) {
            f += wx0[p] * wy0[p] * g[p][0][k] + wx1[p] * wy0[p] * g[p][1][k]
               + wx0[p] * wy1[p] * g[p][2][k] + wx1[p] * wy1[p] * g[p][3][k];
        }
        feat_s[wave][lane + 64 * k] = f * (1.0f / 3.0f);
    }
    __syncthreads();

    // ---- MLP: lane == hidden unit h ----
    float olev[L_][4];
    #pragma unroll
    for (int l = 0; l < L_; ++l) {
        float z = b1[l * HID_ + lane];
        #pragma unroll
        for (int c = 0; c < CPL_; ++c)
            z = fmaf(feat_s[wave][l * CPL_ + c], w1[(l * CPL_ + c) * HID_ + lane], z);
        float sp = fmaxf(z, 0.f) + log1pf(expf(-fabsf(z)));  // softplus
        float sg = 1.0f / (1.0f + expf(-z));                  // softplus'
        const float* w2l = w2 + (l * HID_ + lane) * 5;
        float o0 = sp * w2l[0], o1 = sp * w2l[1], o2 = sp * w2l[2], o3 = sp * w2l[3];
        dz_s[wave][l * HID_ + lane] = sg * w2l[0];            // d(delta)/dz
        #pragma unroll
        for (int s = 1; s < 64; s <<= 1) {
            o0 += __shfl_xor(o0, s, 64);
            o1 += __shfl_xor(o1, s, 64);
            o2 += __shfl_xor(o2, s, 64);
            o3 += __shfl_xor(o3, s, 64);
        }
        olev[l][0] = o0 + b2[l * 5 + 0];
        olev[l][1] = o1 + b2[l * 5 + 1];
        olev[l][2] = o2 + b2[l * 5 + 2];
        olev[l][3] = o3 + b2[l * 5 + 3];
    }
    __syncthreads();

    // ---- dfeat[C] = sum_h dz[l,h] * w1[l,c,h]  for owned channels ----
    float df[3];
    #pragma unroll
    for (int k = 0; k < 3; ++k) {
        int Cc = lane + 64 * k;
        int l  = Cc >> 5;
        const float* w1r = w1 + Cc * HID_;
        const float* dzr = &dz_s[wave][l * HID_];
        float acc = 0.f;
        #pragma unroll
        for (int h4 = 0; h4 < 16; ++h4) {
            float4 wv = *(const float4*)(w1r + 4 * h4);
            float4 dv = *(const float4*)(dzr + 4 * h4);
            acc = fmaf(wv.x, dv.x, acc);
            acc = fmaf(wv.y, dv.y, acc);
            acc = fmaf(wv.z, dv.z, acc);
            acc = fmaf(wv.w, dv.w, acc);
        }
        df[k] = acc;
    }

    // ---- gradient dots (reuse register-resident corner values) ----
    float ax[3] = {0.f, 0.f, 0.f};
    float ay[3] = {0.f, 0.f, 0.f};
    #pragma unroll
    for (int k = 0; k < 3; ++k) {
        #pragma unroll
        for (int p = 0; p < 3; ++p) {
            ax[p] = fmaf(df[k], wy0[p] * (g[p][1][k] - g[p][0][k])
                               + wy1[p] * (g[p][3][k] - g[p][2][k]), ax[p]);
            ay[p] = fmaf(df[k], wx0[p] * (g[p][2][k] - g[p][0][k])
                               + wx1[p] * (g[p][3][k] - g[p][1][k]), ay[p]);
        }
    }
    #pragma unroll
    for (int s = 1; s < 64; s <<= 1) {
        ax[0] += __shfl_xor(ax[0], s, 64);
        ax[1] += __shfl_xor(ax[1], s, 64);
        ax[2] += __shfl_xor(ax[2], s, 64);
        ay[0] += __shfl_xor(ay[0], s, 64);
        ay[1] += __shfl_xor(ay[1], s, 64);
        ay[2] += __shfl_xor(ay[2], s, 64);
    }
    const float F = 128.0f / 3.0f;   // (W/2) * (1/P) * (2/BOX_WARP)
    float gcx = F * (ax[0] + ax[1]);
    float gcy = F * (ay[0] + ay[2]);
    float gcz = F * (ay[1] + ax[2]);

    // ---- epilogue ----
    const float beta = betap[0];
    float r    = sqrtf(cx * cx + cy * cy + cz * cz);
    float smpl = r - 0.5f;
    float delta = 0.f;
    #pragma unroll
    for (int l = 0; l < L_; ++l) delta += olev[l][0];
    float sdf = smpl + delta;

    float ls[L_], sigma = 0.f;
    #pragma unroll
    for (int l = 0; l < L_; ++l) {
        float s = olev[l][0] + smpl;
        ls[l] = (1.0f / (1.0f + expf(s / beta))) / beta;  // sigmoid(-s/beta)/beta
        sigma += ls[l];
    }
    float inv = 1.0f / (sigma + 1e-8f);
    float sem[L_];
    #pragma unroll
    for (int l = 0; l < L_; ++l) sem[l] = ls[l] * inv;

    float racc0 = 0.f, racc1 = 0.f, racc2 = 0.f;
    #pragma unroll
    for (int l = 0; l < L_; ++l) {
        racc0 = fmaf(olev[l][1], sem[l], racc0);
        racc1 = fmaf(olev[l][2], sem[l], racc1);
        racc2 = fmaf(olev[l][3], sem[l], racc2);
    }
    float rgb0 = (1.0f / (1.0f + expf(-racc0))) * 1.002f - 0.001f;
    float rgb1 = (1.0f / (1.0f + expf(-racc1))) * 1.002f - 0.001f;
    float rgb2 = (1.0f / (1.0f + expf(-racc2))) * 1.002f - 0.001f;

    if (lane == 0) {
        float rinv = 1.0f / (r + 1e-8f);
        float* op = out + (size_t)point * 17;
        op[0]  = sdf;
        op[1]  = sigma;
        op[2]  = rgb0;
        op[3]  = rgb1;
        op[4]  = rgb2;
        op[5]  = sem[0]; op[6] = sem[1]; op[7] = sem[2];
        op[8]  = sem[3]; op[9] = sem[4]; op[10] = sem[5];
        op[11] = gcx + cx * rinv;
        op[12] = gcy + cy * rinv;
        op[13] = gcz + cz * rinv;
        op[14] = gcx;
        op[15] = gcy;
        op[16] = gcz;
    }
}

extern "C" void kernel_launch(void* const* d_in, const int* in_sizes, int n_in,
                              void* d_out, int out_size, void* d_ws, size_t ws_size,
                              hipStream_t stream)
{
    const float* planes = (const float*)d_in[0];
    const float* coords = (const float*)d_in[1];
    const float* w1     = (const float*)d_in[2];
    const float* b1     = (const float*)d_in[3];
    const float* w2     = (const float*)d_in[4];
    const float* b2     = (const float*)d_in[5];
    const float* beta   = (const float*)d_in[6];
    float* out = (float*)d_out;

    const size_t need = (size_t)N_ * P_ * C_ * 65536 * sizeof(float); // 302 MB
    if (ws_size >= need) {
        float* tp = (float*)d_ws;
        transpose_kernel<<<N_ * P_ * 2048, 256, 0, stream>>>(planes, tp);
        point_kernel<true><<<(N_ * M_) / 4, 256, 0, stream>>>(
            tp, coords, w1, b1, w2, b2, beta, out);
    } else {
        point_kernel<false><<<(N_ * M_) / 4, 256, 0, stream>>>(
            planes, coords, w1, b1, w2, b2, beta, out);
    }
}